// Round 3
// baseline (131.770 us; speedup 1.0000x reference)
//
#include <hip/hip_runtime.h>
#include <hip/hip_bf16.h>

// out[b,s,t] = ||B(x_s - x_t)||^2 = sq[s] + sq[t] - 2*gram[s,t],  p = x @ B^T
// Round 3: counted-vmcnt 3-buffer pipeline (T3/T4) on both GEMMs.
// Loads for tile t+2 issued at iter t; s_waitcnt vmcnt(N) counted, never 0
// in the main loop; raw s_barrier (no __syncthreads vmcnt(0) drain).

using bf16x8 = __attribute__((ext_vector_type(8))) __bf16;
using f32x4  = __attribute__((ext_vector_type(4))) float;
using fl4    = __attribute__((ext_vector_type(4))) float;
using u16x4  = __attribute__((ext_vector_type(4))) unsigned short;
using u32x4  = __attribute__((ext_vector_type(4))) unsigned int;

#define NB 64
#define NS 512
#define NL 768

__device__ __forceinline__ unsigned short f2bf(float f) {
  unsigned u = __builtin_bit_cast(unsigned, f);
  u += 0x7FFFu + ((u >> 16) & 1u); // RNE
  return (unsigned short)(u >> 16);
}

__device__ __forceinline__ void gload_lds16(const void* g, void* l) {
  __builtin_amdgcn_global_load_lds(
      (const __attribute__((address_space(1))) void*)g,
      (__attribute__((address_space(3))) void*)l, 16, 0, 0);
}

__device__ __forceinline__ bf16x8 cvt_bf8(fl4 a, fl4 b) {
  unsigned r0, r1, r2, r3;
  asm("v_cvt_pk_bf16_f32 %0, %1, %2" : "=v"(r0) : "v"(a[0]), "v"(a[1]));
  asm("v_cvt_pk_bf16_f32 %0, %1, %2" : "=v"(r1) : "v"(a[2]), "v"(a[3]));
  asm("v_cvt_pk_bf16_f32 %0, %1, %2" : "=v"(r2) : "v"(b[0]), "v"(b[1]));
  asm("v_cvt_pk_bf16_f32 %0, %1, %2" : "=v"(r3) : "v"(b[2]), "v"(b[3]));
  u32x4 t = {r0, r1, r2, r3};
  return __builtin_bit_cast(bf16x8, t);
}

#define MEMFENCE asm volatile("" ::: "memory")

// ---------------- kernel 1: convert b (L x L fp32) -> bb bf16 ----------------
__global__ __launch_bounds__(256) void k_cvt_b(const float* __restrict__ b,
                                               unsigned short* __restrict__ bb) {
  const long t = (long)blockIdx.x * 256 + threadIdx.x;
  fl4 v = *(const fl4*)(b + t * 4);
  u16x4 o;
#pragma unroll
  for (int j = 0; j < 4; ++j) o[j] = f2bf(v[j]);
  *(u16x4*)(bb + t * 4) = o;
}

// ---------------- kernel 2: p[M,L] = x[M,L] @ bb^T ----------------
// 128x128 tile, BK=32, 4 waves. A staged fp32, B bf16; 3-buffer pipeline.
__global__ __launch_bounds__(256) void k_proj(const float* __restrict__ x,
                                              const unsigned short* __restrict__ bb,
                                              unsigned short* __restrict__ p) {
  __shared__ __align__(16) float          smA[3][128 * 32]; // 48 KB
  __shared__ __align__(16) unsigned short smB[3][128 * 32]; // 24 KB
  const int tid = threadIdx.x;
  const int w = tid >> 6, l = tid & 63;
  const int wg = ((blockIdx.x & 7) * 192) + (blockIdx.x >> 3);
  const int nt = wg % 6, mt = wg / 6;
  const long m0 = (long)mt * 128, n0 = (long)nt * 128;
  const int wr = (w >> 1) * 64, wc = (w & 1) * 64;

  // A stage: call c covers rows c*32 + tid/8; source col pre-swizzled (rule #21)
  const int arow = tid >> 3;
  const int acol = ((tid & 7) ^ (arow & 7)) * 4; // floats in the 32-col K-slice
  const float* gA = x + (m0 + arow) * (long)NL + acol;
  // B stage: call c covers rows c*64 + tid/4
  const int brow = tid >> 2;
  const int bcol = ((tid & 3) ^ (brow & 3)) * 8; // shorts
  const unsigned short* gB = bb + (n0 + brow) * (long)NL + bcol;

  const int qh = l >> 4, lr = l & 15;
  const int aoff = (wr + lr) * 128;                  // A row byte base
  const int asw1 = (qh * 32) ^ ((lr & 7) << 4);      // swizzled k-off, 1st 16B
  const int asw2 = (qh * 32 + 16) ^ ((lr & 7) << 4); // 2nd 16B
  const int boff = (wc + lr) * 64 + ((qh ^ (lr & 3)) << 4);

  f32x4 acc[4][4] = {};

#define STAGE_A(k0, buf)                                                     \
  {                                                                          \
    char* d_ = (char*)&smA[buf][0] + w * 1024;                               \
    const float* s_ = gA + (k0);                                             \
    gload_lds16(s_ + 0 * 32 * NL, d_ + 0 * 4096);                            \
    gload_lds16(s_ + 1 * 32 * NL, d_ + 1 * 4096);                            \
    gload_lds16(s_ + 2 * 32 * NL, d_ + 2 * 4096);                            \
    gload_lds16(s_ + 3 * 32 * NL, d_ + 3 * 4096);                            \
  }
#define STAGE_B(k0, buf)                                                     \
  {                                                                          \
    char* d_ = (char*)&smB[buf][0] + w * 1024;                               \
    const unsigned short* s_ = gB + (k0);                                    \
    gload_lds16(s_, d_);                                                     \
    gload_lds16(s_ + 64 * NL, d_ + 4096);                                    \
  }
#define COMPUTE(buf)                                                         \
  {                                                                          \
    const char* A_  = (const char*)&smA[buf][0];                             \
    const char* B_  = (const char*)&smB[buf][0];                             \
    bf16x8 fa[4], fb[4];                                                     \
    _Pragma("unroll")                                                        \
    for (int m = 0; m < 4; ++m) {                                            \
      fl4 a0 = *(const fl4*)(A_ + aoff + m * 2048 + asw1);                   \
      fl4 a1 = *(const fl4*)(A_ + aoff + m * 2048 + asw2);                   \
      fa[m] = cvt_bf8(a0, a1);                                               \
    }                                                                        \
    _Pragma("unroll")                                                        \
    for (int n = 0; n < 4; ++n)                                              \
      fb[n] = *(const bf16x8*)(B_ + boff + n * 1024);                        \
    _Pragma("unroll")                                                        \
    for (int m = 0; m < 4; ++m)                                              \
      _Pragma("unroll")                                                      \
      for (int n = 0; n < 4; ++n)                                            \
        acc[m][n] = __builtin_amdgcn_mfma_f32_16x16x32_bf16(fa[m], fb[n],    \
                                                            acc[m][n], 0, 0, 0); \
  }

  // prologue: stage tiles 0,1
  STAGE_A(0, 0)  STAGE_B(0, 0)
  STAGE_A(32, 1) STAGE_B(32, 1)
  int cur = 0, nxt2 = 2;
#pragma unroll 1
  for (int kt = 0; kt < 23; ++kt) {
    asm volatile("s_waitcnt vmcnt(6)" ::: "memory"); // S(kt) landed; S(kt+1) in flight
    __builtin_amdgcn_s_barrier();
    MEMFENCE;
    if (kt < 22) {
      STAGE_A((kt + 2) * 32, nxt2)
      STAGE_B((kt + 2) * 32, nxt2)
    }
    COMPUTE(cur)
    cur = (cur == 2) ? 0 : cur + 1;
    nxt2 = (nxt2 == 2) ? 0 : nxt2 + 1;
  }
  asm volatile("s_waitcnt vmcnt(0)" ::: "memory");
  __builtin_amdgcn_s_barrier();
  MEMFENCE;
  COMPUTE(cur)
#undef STAGE_A
#undef STAGE_B
#undef COMPUTE

  // epilogue: C/D layout col = lane&15, row = (lane>>4)*4 + reg
#pragma unroll
  for (int m = 0; m < 4; ++m) {
    const long rbase = m0 + wr + m * 16 + qh * 4;
#pragma unroll
    for (int n = 0; n < 4; ++n) {
      const long col = n0 + wc + n * 16 + lr;
#pragma unroll
      for (int r = 0; r < 4; ++r)
        p[(rbase + r) * NL + col] = f2bf(acc[m][n][r]);
    }
  }
}

// ---------------- kernel 3: sq[i] = sum_g p[i,g]^2 ----------------
__global__ __launch_bounds__(256) void k_sq(const unsigned short* __restrict__ p,
                                            float* __restrict__ sq) {
  const int row = blockIdx.x * 4 + (threadIdx.x >> 6);
  const int l = threadIdx.x & 63;
  const unsigned short* pr = p + (long)row * NL;
  float s = 0.f;
#pragma unroll
  for (int c = 0; c < 3; ++c) {
    u16x4 v = *(const u16x4*)(pr + (c * 64 + l) * 4);
#pragma unroll
    for (int j = 0; j < 4; ++j) {
      float f = __builtin_bit_cast(float, ((unsigned)v[j]) << 16);
      s += f * f;
    }
  }
#pragma unroll
  for (int d = 32; d >= 1; d >>= 1) s += __shfl_xor(s, d, 64);
  if (l == 0) sq[row] = s;
}

// ------- kernel 4: per-batch gram + epilogue sq[s]+sq[t]-2*gram -------
__global__ __launch_bounds__(256) void k_gram(const unsigned short* __restrict__ p,
                                              const float* __restrict__ sq,
                                              float* __restrict__ out) {
  __shared__ __align__(16) unsigned short smA[3][128 * 32]; // 24 KB
  __shared__ __align__(16) unsigned short smB[3][128 * 32]; // 24 KB
  const int tid = threadIdx.x;
  const int w = tid >> 6, l = tid & 63;
  const int wg = ((blockIdx.x & 7) * 128) + (blockIdx.x >> 3);
  const int batch = wg >> 4, tile = wg & 15;
  const int mt = tile >> 2, nt = tile & 3;
  const unsigned short* pb = p + (long)batch * NS * NL;
  const long m0 = (long)mt * 128, n0 = (long)nt * 128;
  const int wr = (w >> 1) * 64, wc = (w & 1) * 64;

  const int srow = tid >> 2;
  const int scol = ((tid & 3) ^ (srow & 3)) * 8;
  const unsigned short* gA = pb + (m0 + srow) * (long)NL + scol;
  const unsigned short* gB = pb + (n0 + srow) * (long)NL + scol;

  const int qh = l >> 4, lr = l & 15;
  const int aoff = (wr + lr) * 64 + ((qh ^ (lr & 3)) << 4);
  const int boff = (wc + lr) * 64 + ((qh ^ (lr & 3)) << 4);

  f32x4 acc[4][4] = {};

#define STAGE2(k0, buf)                                                      \
  {                                                                          \
    char* da_ = (char*)&smA[buf][0] + w * 1024;                              \
    char* db_ = (char*)&smB[buf][0] + w * 1024;                              \
    gload_lds16(gA + (k0), da_);                                             \
    gload_lds16(gA + (k0) + 64 * NL, da_ + 4096);                            \
    gload_lds16(gB + (k0), db_);                                             \
    gload_lds16(gB + (k0) + 64 * NL, db_ + 4096);                            \
  }
#define COMPUTE2(buf)                                                        \
  {                                                                          \
    const char* A_ = (const char*)&smA[buf][0];                              \
    const char* B_ = (const char*)&smB[buf][0];                              \
    bf16x8 fa[4], fb[4];                                                     \
    _Pragma("unroll")                                                        \
    for (int m = 0; m < 4; ++m)                                              \
      fa[m] = *(const bf16x8*)(A_ + aoff + m * 1024);                        \
    _Pragma("unroll")                                                        \
    for (int n = 0; n < 4; ++n)                                              \
      fb[n] = *(const bf16x8*)(B_ + boff + n * 1024);                        \
    _Pragma("unroll")                                                        \
    for (int m = 0; m < 4; ++m)                                              \
      _Pragma("unroll")                                                      \
      for (int n = 0; n < 4; ++n)                                            \
        acc[m][n] = __builtin_amdgcn_mfma_f32_16x16x32_bf16(fa[m], fb[n],    \
                                                            acc[m][n], 0, 0, 0); \
  }

  STAGE2(0, 0)
  STAGE2(32, 1)
  int cur = 0, nxt2 = 2;
#pragma unroll 1
  for (int kt = 0; kt < 23; ++kt) {
    asm volatile("s_waitcnt vmcnt(4)" ::: "memory");
    __builtin_amdgcn_s_barrier();
    MEMFENCE;
    if (kt < 22) STAGE2((kt + 2) * 32, nxt2)
    COMPUTE2(cur)
    cur = (cur == 2) ? 0 : cur + 1;
    nxt2 = (nxt2 == 2) ? 0 : nxt2 + 1;
  }
  asm volatile("s_waitcnt vmcnt(0)" ::: "memory");
  __builtin_amdgcn_s_barrier();
  MEMFENCE;
  COMPUTE2(cur)
#undef STAGE2
#undef COMPUTE2

  const float* sqb = sq + batch * NS;
  float* outb = out + (long)batch * NS * NS;
  float sqc[4];
#pragma unroll
  for (int n = 0; n < 4; ++n) sqc[n] = sqb[n0 + wc + n * 16 + lr];
#pragma unroll
  for (int m = 0; m < 4; ++m) {
#pragma unroll
    for (int r = 0; r < 4; ++r) {
      const long row = m0 + wr + m * 16 + qh * 4 + r;
      const float sr = sqb[row];
#pragma unroll
      for (int n = 0; n < 4; ++n) {
        const long col = n0 + wc + n * 16 + lr;
        outb[row * NS + col] = sr + sqc[n] - 2.0f * acc[m][n][r];
      }
    }
  }
}

extern "C" void kernel_launch(void* const* d_in, const int* in_sizes, int n_in,
                              void* d_out, int out_size, void* d_ws, size_t ws_size,
                              hipStream_t stream) {
  (void)in_sizes; (void)n_in; (void)out_size; (void)ws_size;
  const float* x = (const float*)d_in[0]; // [B,S,L] fp32
  const float* b = (const float*)d_in[1]; // [L,L] fp32
  float* out = (float*)d_out;             // [B,S,S] fp32
  char* ws = (char*)d_ws;
  unsigned short* bb = (unsigned short*)ws;              // 1,179,648 B
  float* sq          = (float*)(ws + 1179648);           //   131,072 B
  unsigned short* p  = (unsigned short*)(ws + 1310720);  // 50,331,648 B

  k_cvt_b<<<576, 256, 0, stream>>>(b, bb);
  k_proj <<<1536, 256, 0, stream>>>(x, bb, p);
  k_sq   <<<8192, 256, 0, stream>>>(p, sq);
  k_gram <<<1024, 256, 0, stream>>>(p, sq, out);
}

// Round 4
// 120.175 us; speedup vs baseline: 1.0965x; 1.0965x over previous
//
#include <hip/hip_runtime.h>
#include <hip/hip_bf16.h>

// out[b,s,t] = ||B(x_s - x_t)||^2 = sq[s] + sq[t] - 2*gram[s,t],  p = x @ B^T
// Round 4: k_proj A-path = reg-staged bf16 (T14 one-phase lead), padded
// [128][40] chunk-XOR A tile; B swizzle fixed to (row>>1)&3; 36 KB LDS.

using bf16x8 = __attribute__((ext_vector_type(8))) __bf16;
using f32x4  = __attribute__((ext_vector_type(4))) float;
using fl4    = __attribute__((ext_vector_type(4))) float;
using u16x4  = __attribute__((ext_vector_type(4))) unsigned short;
using u32x4  = __attribute__((ext_vector_type(4))) unsigned int;

#define NB 64
#define NS 512
#define NL 768

__device__ __forceinline__ unsigned short f2bf(float f) {
  unsigned u = __builtin_bit_cast(unsigned, f);
  u += 0x7FFFu + ((u >> 16) & 1u); // RNE
  return (unsigned short)(u >> 16);
}

__device__ __forceinline__ void gload_lds16(const void* g, void* l) {
  __builtin_amdgcn_global_load_lds(
      (const __attribute__((address_space(1))) void*)g,
      (__attribute__((address_space(3))) void*)l, 16, 0, 0);
}

#define MEMFENCE asm volatile("" ::: "memory")

// ---------------- kernel 1: convert b (L x L fp32) -> bb bf16 ----------------
__global__ __launch_bounds__(256) void k_cvt_b(const float* __restrict__ b,
                                               unsigned short* __restrict__ bb) {
  const long t = (long)blockIdx.x * 256 + threadIdx.x;
  fl4 v = *(const fl4*)(b + t * 4);
  u16x4 o;
#pragma unroll
  for (int j = 0; j < 4; ++j) o[j] = f2bf(v[j]);
  *(u16x4*)(bb + t * 4) = o;
}

// ---------------- kernel 2: p[M,L] = x[M,L] @ bb^T ----------------
// 128x128 tile, BK=32, 4 waves. A: global fp32 -> regs -> cvt -> bf16 LDS
// [128][40] (80B rows, chunk-XOR (row>>3)&3). B: gload_lds, source chunk
// pre-swizzle (row>>1)&3. Double buffer, T14 issue-early, 1 barrier/iter.
__global__ __launch_bounds__(256) void k_proj(const float* __restrict__ x,
                                              const unsigned short* __restrict__ bb,
                                              unsigned short* __restrict__ p) {
  __shared__ __align__(16) unsigned short smA[2][128 * 40]; // 2 x 10240 B
  __shared__ __align__(16) unsigned short smB[2][128 * 32]; // 2 x  8192 B
  const int tid = threadIdx.x;
  const int w = tid >> 6, l = tid & 63;
  const int wg = ((blockIdx.x & 7) * 192) + (blockIdx.x >> 3);
  const int nt = wg % 6, mt = wg / 6;
  const long m0 = (long)mt * 128, n0 = (long)nt * 128;
  const int wr = (w >> 1) * 64, wc = (w & 1) * 64;

  // A reg-stage: thread covers row = tid>>1, floats k = (tid&1)*16 .. +16
  const int arow = tid >> 1, ah = tid & 1;
  const float* gA = x + (m0 + arow) * (long)NL + ah * 16;
  const int as_ = (arow >> 3) & 3;                 // chunk-XOR for this row
  const int awr0 = arow * 80 + (((2 * ah + 0) ^ as_) << 4);
  const int awr1 = arow * 80 + (((2 * ah + 1) ^ as_) << 4);

  // B stage via gload_lds: row = tid>>2, source chunk pre-swizzled
  const int brow = tid >> 2;
  const int bcol = ((tid & 3) ^ ((brow >> 1) & 3)) * 8; // shorts
  const unsigned short* gB = bb + (n0 + brow) * (long)NL + bcol;

  const int qh = l >> 4, lr = l & 15;
  int aro[4]; // A-frag byte offsets, row = wr + m*16 + lr
#pragma unroll
  for (int m = 0; m < 4; ++m) {
    const int r = wr + m * 16 + lr;
    aro[m] = r * 80 + ((qh ^ ((r >> 3) & 3)) << 4);
  }
  const int boff = (wc + lr) * 64 + ((qh ^ ((lr >> 1) & 3)) << 4);

  f32x4 acc[4][4] = {};
  fl4 ar0, ar1, ar2, ar3;

#define ISSUE_B(k0, buf)                                                     \
  {                                                                          \
    char* d_ = (char*)&smB[buf][0] + w * 1024;                               \
    gload_lds16(gB + (k0), d_);                                              \
    gload_lds16(gB + (k0) + 64 * NL, d_ + 4096);                             \
  }
#define ISSUE_A(k0)                                                          \
  {                                                                          \
    ar0 = *(const fl4*)(gA + (k0));                                          \
    ar1 = *(const fl4*)(gA + (k0) + 4);                                      \
    ar2 = *(const fl4*)(gA + (k0) + 8);                                      \
    ar3 = *(const fl4*)(gA + (k0) + 12);                                     \
  }
#define WRITE_A(buf)                                                         \
  {                                                                          \
    unsigned q0, q1, q2, q3, q4, q5, q6, q7;                                 \
    asm("v_cvt_pk_bf16_f32 %0, %1, %2" : "=v"(q0) : "v"(ar0[0]), "v"(ar0[1]));\
    asm("v_cvt_pk_bf16_f32 %0, %1, %2" : "=v"(q1) : "v"(ar0[2]), "v"(ar0[3]));\
    asm("v_cvt_pk_bf16_f32 %0, %1, %2" : "=v"(q2) : "v"(ar1[0]), "v"(ar1[1]));\
    asm("v_cvt_pk_bf16_f32 %0, %1, %2" : "=v"(q3) : "v"(ar1[2]), "v"(ar1[3]));\
    asm("v_cvt_pk_bf16_f32 %0, %1, %2" : "=v"(q4) : "v"(ar2[0]), "v"(ar2[1]));\
    asm("v_cvt_pk_bf16_f32 %0, %1, %2" : "=v"(q5) : "v"(ar2[2]), "v"(ar2[3]));\
    asm("v_cvt_pk_bf16_f32 %0, %1, %2" : "=v"(q6) : "v"(ar3[0]), "v"(ar3[1]));\
    asm("v_cvt_pk_bf16_f32 %0, %1, %2" : "=v"(q7) : "v"(ar3[2]), "v"(ar3[3]));\
    u32x4 c0 = {q0, q1, q2, q3}, c1 = {q4, q5, q6, q7};                      \
    char* base_ = (char*)&smA[buf][0];                                       \
    *(u32x4*)(base_ + awr0) = c0;                                            \
    *(u32x4*)(base_ + awr1) = c1;                                            \
  }
#define COMPUTE(buf)                                                         \
  {                                                                          \
    const char* A_ = (const char*)&smA[buf][0];                              \
    const char* B_ = (const char*)&smB[buf][0];                              \
    bf16x8 fa[4], fb[4];                                                     \
    _Pragma("unroll")                                                        \
    for (int m = 0; m < 4; ++m) fa[m] = *(const bf16x8*)(A_ + aro[m]);       \
    _Pragma("unroll")                                                        \
    for (int n = 0; n < 4; ++n) fb[n] = *(const bf16x8*)(B_ + boff + n * 1024);\
    _Pragma("unroll")                                                        \
    for (int m = 0; m < 4; ++m)                                              \
      _Pragma("unroll")                                                      \
      for (int n = 0; n < 4; ++n)                                            \
        acc[m][n] = __builtin_amdgcn_mfma_f32_16x16x32_bf16(fa[m], fb[n],    \
                                                            acc[m][n], 0, 0, 0); \
  }

  // prologue: tile 0
  ISSUE_B(0, 0)
  ISSUE_A(0)
  asm volatile("s_waitcnt vmcnt(0)" ::: "memory");
  WRITE_A(0)
  asm volatile("s_waitcnt lgkmcnt(0)" ::: "memory");
  __builtin_amdgcn_s_barrier();
  MEMFENCE;
  int cur = 0;
#pragma unroll 1
  for (int kt = 0; kt < 24; ++kt) {
    if (kt < 23) {
      ISSUE_B((kt + 1) * 32, cur ^ 1)  // into freed buffer; flies over compute
      ISSUE_A((kt + 1) * 32)           // fp32 -> regs; flies over compute
    }
    COMPUTE(cur)
    if (kt < 23) {
      asm volatile("s_waitcnt vmcnt(0)" ::: "memory"); // A-regs + B landed
      WRITE_A(cur ^ 1)
      asm volatile("s_waitcnt lgkmcnt(0)" ::: "memory");
      __builtin_amdgcn_s_barrier();
      MEMFENCE;
      cur ^= 1;
    }
  }
#undef ISSUE_B
#undef ISSUE_A
#undef WRITE_A
#undef COMPUTE

  // epilogue: C/D layout col = lane&15, row = (lane>>4)*4 + reg
#pragma unroll
  for (int m = 0; m < 4; ++m) {
    const long rbase = m0 + wr + m * 16 + qh * 4;
#pragma unroll
    for (int n = 0; n < 4; ++n) {
      const long col = n0 + wc + n * 16 + lr;
#pragma unroll
      for (int r = 0; r < 4; ++r)
        p[(rbase + r) * NL + col] = f2bf(acc[m][n][r]);
    }
  }
}

// ---------------- kernel 3: sq[i] = sum_g p[i,g]^2 ----------------
__global__ __launch_bounds__(256) void k_sq(const unsigned short* __restrict__ p,
                                            float* __restrict__ sq) {
  const int row = blockIdx.x * 4 + (threadIdx.x >> 6);
  const int l = threadIdx.x & 63;
  const unsigned short* pr = p + (long)row * NL;
  float s = 0.f;
#pragma unroll
  for (int c = 0; c < 3; ++c) {
    u16x4 v = *(const u16x4*)(pr + (c * 64 + l) * 4);
#pragma unroll
    for (int j = 0; j < 4; ++j) {
      float f = __builtin_bit_cast(float, ((unsigned)v[j]) << 16);
      s += f * f;
    }
  }
#pragma unroll
  for (int d = 32; d >= 1; d >>= 1) s += __shfl_xor(s, d, 64);
  if (l == 0) sq[row] = s;
}

// ------- kernel 4: per-batch gram + epilogue sq[s]+sq[t]-2*gram -------
__global__ __launch_bounds__(256) void k_gram(const unsigned short* __restrict__ p,
                                              const float* __restrict__ sq,
                                              float* __restrict__ out) {
  __shared__ __align__(16) unsigned short smA[3][128 * 32];
  __shared__ __align__(16) unsigned short smB[3][128 * 32];
  const int tid = threadIdx.x;
  const int w = tid >> 6, l = tid & 63;
  const int wg = ((blockIdx.x & 7) * 128) + (blockIdx.x >> 3);
  const int batch = wg >> 4, tile = wg & 15;
  const int mt = tile >> 2, nt = tile & 3;
  const unsigned short* pb = p + (long)batch * NS * NL;
  const long m0 = (long)mt * 128, n0 = (long)nt * 128;
  const int wr = (w >> 1) * 64, wc = (w & 1) * 64;

  const int srow = tid >> 2;
  const int scol = ((tid & 3) ^ ((srow >> 1) & 3)) * 8; // fixed swizzle bits
  const unsigned short* gA = pb + (m0 + srow) * (long)NL + scol;
  const unsigned short* gB = pb + (n0 + srow) * (long)NL + scol;

  const int qh = l >> 4, lr = l & 15;
  const int aoff = (wr + lr) * 64 + ((qh ^ ((lr >> 1) & 3)) << 4);
  const int boff = (wc + lr) * 64 + ((qh ^ ((lr >> 1) & 3)) << 4);

  f32x4 acc[4][4] = {};

#define STAGE2(k0, buf)                                                      \
  {                                                                          \
    char* da_ = (char*)&smA[buf][0] + w * 1024;                              \
    char* db_ = (char*)&smB[buf][0] + w * 1024;                              \
    gload_lds16(gA + (k0), da_);                                             \
    gload_lds16(gA + (k0) + 64 * NL, da_ + 4096);                            \
    gload_lds16(gB + (k0), db_);                                             \
    gload_lds16(gB + (k0) + 64 * NL, db_ + 4096);                            \
  }
#define COMPUTE2(buf)                                                        \
  {                                                                          \
    const char* A_ = (const char*)&smA[buf][0];                              \
    const char* B_ = (const char*)&smB[buf][0];                              \
    bf16x8 fa[4], fb[4];                                                     \
    _Pragma("unroll")                                                        \
    for (int m = 0; m < 4; ++m)                                              \
      fa[m] = *(const bf16x8*)(A_ + aoff + m * 1024);                        \
    _Pragma("unroll")                                                        \
    for (int n = 0; n < 4; ++n)                                              \
      fb[n] = *(const bf16x8*)(B_ + boff + n * 1024);                        \
    _Pragma("unroll")                                                        \
    for (int m = 0; m < 4; ++m)                                              \
      _Pragma("unroll")                                                      \
      for (int n = 0; n < 4; ++n)                                            \
        acc[m][n] = __builtin_amdgcn_mfma_f32_16x16x32_bf16(fa[m], fb[n],    \
                                                            acc[m][n], 0, 0, 0); \
  }

  STAGE2(0, 0)
  STAGE2(32, 1)
  int cur = 0, nxt2 = 2;
#pragma unroll 1
  for (int kt = 0; kt < 23; ++kt) {
    asm volatile("s_waitcnt vmcnt(4)" ::: "memory");
    __builtin_amdgcn_s_barrier();
    MEMFENCE;
    if (kt < 22) STAGE2((kt + 2) * 32, nxt2)
    COMPUTE2(cur)
    cur = (cur == 2) ? 0 : cur + 1;
    nxt2 = (nxt2 == 2) ? 0 : nxt2 + 1;
  }
  asm volatile("s_waitcnt vmcnt(0)" ::: "memory");
  __builtin_amdgcn_s_barrier();
  MEMFENCE;
  COMPUTE2(cur)
#undef STAGE2
#undef COMPUTE2

  const float* sqb = sq + batch * NS;
  float* outb = out + (long)batch * NS * NS;
  float sqc[4];
#pragma unroll
  for (int n = 0; n < 4; ++n) sqc[n] = sqb[n0 + wc + n * 16 + lr];
#pragma unroll
  for (int m = 0; m < 4; ++m) {
#pragma unroll
    for (int r = 0; r < 4; ++r) {
      const long row = m0 + wr + m * 16 + qh * 4 + r;
      const float sr = sqb[row];
#pragma unroll
      for (int n = 0; n < 4; ++n) {
        const long col = n0 + wc + n * 16 + lr;
        outb[row * NS + col] = sr + sqc[n] - 2.0f * acc[m][n][r];
      }
    }
  }
}

extern "C" void kernel_launch(void* const* d_in, const int* in_sizes, int n_in,
                              void* d_out, int out_size, void* d_ws, size_t ws_size,
                              hipStream_t stream) {
  (void)in_sizes; (void)n_in; (void)out_size; (void)ws_size;
  const float* x = (const float*)d_in[0]; // [B,S,L] fp32
  const float* b = (const float*)d_in[1]; // [L,L] fp32
  float* out = (float*)d_out;             // [B,S,S] fp32
  char* ws = (char*)d_ws;
  unsigned short* bb = (unsigned short*)ws;              // 1,179,648 B
  float* sq          = (float*)(ws + 1179648);           //   131,072 B
  unsigned short* p  = (unsigned short*)(ws + 1310720);  // 50,331,648 B

  k_cvt_b<<<576, 256, 0, stream>>>(b, bb);
  k_proj <<<1536, 256, 0, stream>>>(x, bb, p);
  k_sq   <<<8192, 256, 0, stream>>>(p, sq);
  k_gram <<<1024, 256, 0, stream>>>(p, sq, out);
}